// Round 8
// baseline (43.324 us; speedup 1.0000x reference)
//
#include <hip/hip_runtime.h>

#define Ndim 128
#define Cdim 3
#define Hdim 256
#define Wdim 256
#define HW (Hdim * Wdim)
#define MAXNORM_F 5.371920351148152f

typedef float vf2 __attribute__((ext_vector_type(2)));
typedef unsigned int uint32;

__device__ __forceinline__ void mm3f(const float a[3][3], const float b[3][3], float c[3][3]) {
    #pragma unroll
    for (int i = 0; i < 3; ++i)
        #pragma unroll
        for (int j = 0; j < 3; ++j) {
            float s = 0.0f;
            #pragma unroll
            for (int k = 0; k < 3; ++k) s = fmaf(a[i][k], b[k][j], s);
            c[i][j] = s;
        }
}

// One thread per batch element: expm of padded 3x3 affine matrix (fp32 Pade-13).
__global__ void expm_kernel(const float* __restrict__ theta, float* __restrict__ thOut) {
    int n = blockIdx.x * blockDim.x + threadIdx.x;
    if (n >= Ndim) return;

    const float b[14] = {6.476475253248e+16f, 3.238237626624e+16f, 7771770303897600.0f,
                         1187353796428800.0f, 129060195264000.0f, 10559470521600.0f,
                         670442572800.0f, 33522128640.0f, 1323241920.0f, 40840800.0f,
                         960960.0f, 16380.0f, 182.0f, 1.0f};

    float A[3][3];
    #pragma unroll
    for (int j = 0; j < 3; ++j) {
        A[0][j] = theta[n * 6 + j];
        A[1][j] = theta[n * 6 + 3 + j];
        A[2][j] = 0.0f;
    }

    float fro2 = 0.0f;
    #pragma unroll
    for (int i = 0; i < 3; ++i)
        #pragma unroll
        for (int j = 0; j < 3; ++j) fro2 = fmaf(A[i][j], A[i][j], fro2);
    float fro = sqrtf(fro2);

    float nsq = fmaxf(0.0f, ceilf(log2f(fro / MAXNORM_F)));
    int k = (int)nsq;
    float sc = exp2f(-nsq);
    #pragma unroll
    for (int i = 0; i < 3; ++i)
        #pragma unroll
        for (int j = 0; j < 3; ++j) A[i][j] *= sc;

    float A2[3][3], A4[3][3], A6[3][3], P[3][3], Wm[3][3], T[3][3], U[3][3], V[3][3];
    mm3f(A, A, A2);
    mm3f(A2, A2, A4);
    mm3f(A4, A2, A6);

    #pragma unroll
    for (int i = 0; i < 3; ++i)
        #pragma unroll
        for (int j = 0; j < 3; ++j)
            P[i][j] = b[13] * A6[i][j] + b[11] * A4[i][j] + b[9] * A2[i][j];
    mm3f(A6, P, T);
    #pragma unroll
    for (int i = 0; i < 3; ++i)
        #pragma unroll
        for (int j = 0; j < 3; ++j)
            Wm[i][j] = T[i][j] + b[7] * A6[i][j] + b[5] * A4[i][j] + b[3] * A2[i][j]
                       + (i == j ? b[1] : 0.0f);
    mm3f(A, Wm, U);

    #pragma unroll
    for (int i = 0; i < 3; ++i)
        #pragma unroll
        for (int j = 0; j < 3; ++j)
            P[i][j] = b[12] * A6[i][j] + b[10] * A4[i][j] + b[8] * A2[i][j];
    mm3f(A6, P, T);
    #pragma unroll
    for (int i = 0; i < 3; ++i)
        #pragma unroll
        for (int j = 0; j < 3; ++j)
            V[i][j] = T[i][j] + b[6] * A6[i][j] + b[4] * A4[i][j] + b[2] * A2[i][j]
                      + (i == j ? b[0] : 0.0f);

    float M[3][6];
    #pragma unroll
    for (int i = 0; i < 3; ++i)
        #pragma unroll
        for (int j = 0; j < 3; ++j) {
            M[i][j]     = U[i][j] + V[i][j];
            M[i][j + 3] = V[i][j] - U[i][j];
        }
    #pragma unroll
    for (int col = 0; col < 3; ++col) {
        int piv = col;
        float best = fabsf(M[col][col]);
        for (int r = col + 1; r < 3; ++r) {
            float v = fabsf(M[r][col]);
            if (v > best) { best = v; piv = r; }
        }
        if (piv != col) {
            #pragma unroll
            for (int j = 0; j < 6; ++j) {
                float t = M[col][j]; M[col][j] = M[piv][j]; M[piv][j] = t;
            }
        }
        float inv = 1.0f / M[col][col];
        #pragma unroll
        for (int j = 0; j < 6; ++j) M[col][j] *= inv;
        #pragma unroll
        for (int r = 0; r < 3; ++r) {
            if (r == col) continue;
            float f = M[r][col];
            #pragma unroll
            for (int j = 0; j < 6; ++j) M[r][j] -= f * M[col][j];
        }
    }
    float R[3][3];
    #pragma unroll
    for (int i = 0; i < 3; ++i)
        #pragma unroll
        for (int j = 0; j < 3; ++j) R[i][j] = M[i][j + 3];

    for (int i = 0; i < 16; ++i) {
        if (i < k) {
            float Rn[3][3];
            mm3f(R, R, Rn);
            #pragma unroll
            for (int a = 0; a < 3; ++a)
                #pragma unroll
                for (int c = 0; c < 3; ++c) R[a][c] = Rn[a][c];
        }
    }

    #pragma unroll
    for (int j = 0; j < 3; ++j) {
        thOut[n * 6 + j]     = (float)R[0][j];
        thOut[n * 6 + 3 + j] = (float)R[1][j];
    }
}

// Fused affine_grid + bilinear grid_sample (zeros padding, align_corners=True).
// Block = 32x32 output tile of one image; 256 threads, each a 2x2 quad.
// Phase 1: stage the block's (uniform) input bounding window (56 cols x rn+1
//   rows x 3 ch) into LDS with global_load_lds dwordx4 — each input cache
//   line touched ONCE per block. LDS layout [row][ch][56] floats, chunk c ->
//   LDS byte c*16 (linear dest as HW requires), per-lane global source.
// Phase 2: per-pixel bilinear from LDS. EACH of the 4 corner slots is clamped
//   INDEPENDENTLY into the staged window (R7 bug: clamping the pair base and
//   reading +1 fed real-weight corners the wrong neighbor at image edges).
//   Any slot displaced by clamping provably carries weight 0, and row rn /
//   col 55 are always staged, so displaced reads hit written LDS.
__global__ __launch_bounds__(256) void sample_kernel(const float* __restrict__ x,
                                                     const float* __restrict__ th,
                                                     float* __restrict__ out) {
    __shared__ float lds[10240];  // 2560 chunks * 16B = 40960 B

    // 8x8 tiles/image * 128 images = 8192 blocks; bijective XCD swizzle
    const int nwg_per_xcd = 8192 / 8;
    int bid = blockIdx.x;
    int wgid = (bid & 7) * nwg_per_xcd + (bid >> 3);

    int tw  = wgid & 7;
    int thp = (wgid >> 3) & 7;
    int n   = wgid >> 6;

    int tid = threadIdx.x;
    int wp = tid & 15, hp = tid >> 4;
    int w0 = (tw << 5) + (wp << 1);
    int h0 = (thp << 5) + (hp << 1);

    const float* t = th + n * 6;
    float t0 = t[0], t1 = t[1], t2 = t[2], t3 = t[3], t4 = t[4], t5 = t[5];

    float Cx = 127.5f * (t2 - t0 - t1 + 1.0f);
    float Cy = 127.5f * (t5 - t3 - t4 + 1.0f);

    // block-uniform bounding box of sample coords (pad +-1 for fp slack, +1 corner)
    float fwA = (float)(tw << 5),  fwB = fwA + 31.0f;
    float fhA = (float)(thp << 5), fhB = fhA + 31.0f;
    float xlo = fminf(fwA * t0, fwB * t0) + fminf(fhA * t1, fhB * t1) + Cx;
    float xhi = fmaxf(fwA * t0, fwB * t0) + fmaxf(fhA * t1, fhB * t1) + Cx;
    float ylo = fminf(fwA * t3, fwB * t3) + fminf(fhA * t4, fhB * t4) + Cy;
    float yhi = fmaxf(fwA * t3, fwB * t3) + fmaxf(fhA * t4, fhB * t4) + Cy;
    int Xlo = (int)floorf(xlo) - 1, Xhi = (int)floorf(xhi) + 2;
    int Ylo = (int)floorf(ylo) - 1, Yhi = (int)floorf(yhi) + 2;
    int cn = Xhi - Xlo + 1;
    int rn = Yhi - Ylo + 1;

    size_t nbase = (size_t)n * Cdim * HW;

    // quad sample coords
    float ix00 = fmaf((float)w0, t0, fmaf((float)h0, t1, Cx));
    float iy00 = fmaf((float)w0, t3, fmaf((float)h0, t4, Cy));
    float ixq[2][2] = {{ix00, ix00 + t0}, {ix00 + t1, ix00 + t0 + t1}};
    float iyq[2][2] = {{iy00, iy00 + t3}, {iy00 + t4, iy00 + t3 + t4}};

    bool fast = (cn <= 52) && (rn <= 55) && (rn >= 1) && (cn >= 1);

    if (fast) {
        int bxw = (min(max(Xlo, 0), Wdim - 56)) & ~3;  // 16B-aligned window base col
        int byw = min(max(Ylo, 0), Hdim - rn);

        // ---- Phase 1: stage (rn+1) rows x 56 cols x 3 ch ----
        int totc  = 42 * (rn + 1);           // 16B chunks (42 = 3ch * 14 chunks/row)
        int iters = (totc + 255) >> 8;       // <= 10
        const float* gbase = x + nbase;
        for (int it = 0; it < iters; ++it) {
            int c = (it << 8) + tid;
            int row = c / 42;
            int rem = c - row * 42;
            row = min(row, rn);                       // overshoot -> re-stage last row
            int ch   = rem / 14;
            int colc = rem - ch * 14;
            int srow = min(byw + row, Hdim - 1);      // extra row clamped in-image
            const float* gp = gbase + (size_t)ch * HW + (srow << 8) + bxw + (colc << 2);
            __builtin_amdgcn_global_load_lds(
                (const __attribute__((address_space(1))) uint32*)gp,
                (__attribute__((address_space(3))) uint32*)((uint32*)lds + ((size_t)c << 2)),
                16, 0, 0);
        }
        __syncthreads();

        // ---- Phase 2: per-pixel bilinear from LDS (per-corner clamped slots) ----
        float res[2][2][3];
        #pragma unroll
        for (int p = 0; p < 2; ++p)
            #pragma unroll
            for (int q = 0; q < 2; ++q) {
                float ix = ixq[p][q], iy = iyq[p][q];
                float fx = floorf(ix), fy = floorf(iy);
                int x0i = (int)fx, y0i = (int)fy;
                float wx1 = ix - fx, wx0 = 1.0f - wx1;
                float wy1 = iy - fy, wy0 = 1.0f - wy1;
                float mx0 = ((unsigned)x0i       < (unsigned)Wdim) ? 1.0f : 0.0f;
                float mx1 = ((unsigned)(x0i + 1) < (unsigned)Wdim) ? 1.0f : 0.0f;
                float my0 = ((unsigned)y0i       < (unsigned)Hdim) ? 1.0f : 0.0f;
                float my1 = ((unsigned)(y0i + 1) < (unsigned)Hdim) ? 1.0f : 0.0f;
                float wxm0 = wx0 * mx0, wxm1 = wx1 * mx1;
                float wym0 = wy0 * my0, wym1 = wy1 * my1;

                // independent per-corner slots; displaced => weight 0
                int lx0 = min(max(x0i - bxw, 0), 55);
                int lx1 = min(max(x0i + 1 - bxw, 0), 55);
                int ly0 = min(max(y0i - byw, 0), rn);
                int ly1 = min(max(y0i + 1 - byw, 0), rn);
                int r0 = ly0 * 168, r1 = ly1 * 168;   // [row][ch][56] dword index
                #pragma unroll
                for (int c = 0; c < Cdim; ++c) {
                    int b0 = r0 + c * 56;
                    int b1 = r1 + c * 56;
                    float v00 = lds[b0 + lx0], v01 = lds[b0 + lx1];
                    float v10 = lds[b1 + lx0], v11 = lds[b1 + lx1];
                    float top = fmaf(v01, wxm1, v00 * wxm0);
                    float bot = fmaf(v11, wxm1, v10 * wxm0);
                    res[p][q][c] = fmaf(wym1, bot, wym0 * top);
                }
            }

        size_t p0 = (size_t)h0 * Wdim + w0;
        #pragma unroll
        for (int c = 0; c < Cdim; ++c) {
            vf2 r0 = {res[0][0][c], res[0][1][c]};
            vf2 r1 = {res[1][0][c], res[1][1][c]};
            __builtin_nontemporal_store(r0, (vf2*)(out + nbase + (size_t)c * HW + p0));
            __builtin_nontemporal_store(r1, (vf2*)(out + nbase + (size_t)c * HW + p0 + Wdim));
        }
    } else {
        // exact fallback: per-pixel global gathers (block-uniform branch)
        const float* img0 = x + nbase;
        #pragma unroll
        for (int p = 0; p < 2; ++p)
            #pragma unroll
            for (int q = 0; q < 2; ++q) {
                float ix = ixq[p][q], iy = iyq[p][q];
                float fx = floorf(ix), fy = floorf(iy);
                int ix0 = (int)fx, iy0 = (int)fy;
                float wx1 = ix - fx, wx0 = 1.0f - wx1;
                float wy1 = iy - fy, wy0 = 1.0f - wy1;
                float mx0 = ((unsigned)ix0       < (unsigned)Wdim) ? 1.0f : 0.0f;
                float mx1 = ((unsigned)(ix0 + 1) < (unsigned)Wdim) ? 1.0f : 0.0f;
                float my0 = ((unsigned)iy0       < (unsigned)Hdim) ? 1.0f : 0.0f;
                float my1 = ((unsigned)(iy0 + 1) < (unsigned)Hdim) ? 1.0f : 0.0f;
                int xc0 = min(max(ix0, 0), Wdim - 1);
                int xc1 = min(max(ix0 + 1, 0), Wdim - 1);
                int yc0 = min(max(iy0, 0), Hdim - 1);
                int yc1 = min(max(iy0 + 1, 0), Hdim - 1);
                float w00 = wy0 * wx0 * my0 * mx0;
                float w01 = wy0 * wx1 * my0 * mx1;
                float w10 = wy1 * wx0 * my1 * mx0;
                float w11 = wy1 * wx1 * my1 * mx1;
                int o00 = yc0 * Wdim + xc0, o01 = yc0 * Wdim + xc1;
                int o10 = yc1 * Wdim + xc0, o11 = yc1 * Wdim + xc1;
                #pragma unroll
                for (int c = 0; c < Cdim; ++c) {
                    const float* img = img0 + (size_t)c * HW;
                    float r = fmaf(img[o00], w00, fmaf(img[o01], w01,
                              fmaf(img[o10], w10, img[o11] * w11)));
                    out[nbase + (size_t)c * HW + (size_t)(h0 + p) * Wdim + (w0 + q)] = r;
                }
            }
    }
}

extern "C" void kernel_launch(void* const* d_in, const int* in_sizes, int n_in,
                              void* d_out, int out_size, void* d_ws, size_t ws_size,
                              hipStream_t stream) {
    const float* x     = (const float*)d_in[0];
    const float* theta = (const float*)d_in[1];
    float* out = (float*)d_out;
    float* th  = (float*)d_ws;  // 128*6 floats of scratch

    expm_kernel<<<1, 128, 0, stream>>>(theta, th);

    int nblocks = 8192;
    sample_kernel<<<nblocks, 256, 0, stream>>>(x, th, out);
}

// Round 9
// 42.876 us; speedup vs baseline: 1.0104x; 1.0104x over previous
//
#include <hip/hip_runtime.h>

#define Ndim 128
#define Cdim 3
#define Hdim 256
#define Wdim 256
#define HW (Hdim * Wdim)
#define MAXNORM_F 5.371920351148152f

typedef float vf2 __attribute__((ext_vector_type(2)));
typedef unsigned int uint32;

__device__ __forceinline__ void mm3f(const float a[3][3], const float b[3][3], float c[3][3]) {
    #pragma unroll
    for (int i = 0; i < 3; ++i)
        #pragma unroll
        for (int j = 0; j < 3; ++j) {
            float s = 0.0f;
            #pragma unroll
            for (int k = 0; k < 3; ++k) s = fmaf(a[i][k], b[k][j], s);
            c[i][j] = s;
        }
}

// One thread per batch element: expm of padded 3x3 affine matrix (fp32 Pade-13).
__global__ void expm_kernel(const float* __restrict__ theta, float* __restrict__ thOut) {
    int n = blockIdx.x * blockDim.x + threadIdx.x;
    if (n >= Ndim) return;

    const float b[14] = {6.476475253248e+16f, 3.238237626624e+16f, 7771770303897600.0f,
                         1187353796428800.0f, 129060195264000.0f, 10559470521600.0f,
                         670442572800.0f, 33522128640.0f, 1323241920.0f, 40840800.0f,
                         960960.0f, 16380.0f, 182.0f, 1.0f};

    float A[3][3];
    #pragma unroll
    for (int j = 0; j < 3; ++j) {
        A[0][j] = theta[n * 6 + j];
        A[1][j] = theta[n * 6 + 3 + j];
        A[2][j] = 0.0f;
    }

    float fro2 = 0.0f;
    #pragma unroll
    for (int i = 0; i < 3; ++i)
        #pragma unroll
        for (int j = 0; j < 3; ++j) fro2 = fmaf(A[i][j], A[i][j], fro2);
    float fro = sqrtf(fro2);

    float nsq = fmaxf(0.0f, ceilf(log2f(fro / MAXNORM_F)));
    int k = (int)nsq;
    float sc = exp2f(-nsq);
    #pragma unroll
    for (int i = 0; i < 3; ++i)
        #pragma unroll
        for (int j = 0; j < 3; ++j) A[i][j] *= sc;

    float A2[3][3], A4[3][3], A6[3][3], P[3][3], Wm[3][3], T[3][3], U[3][3], V[3][3];
    mm3f(A, A, A2);
    mm3f(A2, A2, A4);
    mm3f(A4, A2, A6);

    #pragma unroll
    for (int i = 0; i < 3; ++i)
        #pragma unroll
        for (int j = 0; j < 3; ++j)
            P[i][j] = b[13] * A6[i][j] + b[11] * A4[i][j] + b[9] * A2[i][j];
    mm3f(A6, P, T);
    #pragma unroll
    for (int i = 0; i < 3; ++i)
        #pragma unroll
        for (int j = 0; j < 3; ++j)
            Wm[i][j] = T[i][j] + b[7] * A6[i][j] + b[5] * A4[i][j] + b[3] * A2[i][j]
                       + (i == j ? b[1] : 0.0f);
    mm3f(A, Wm, U);

    #pragma unroll
    for (int i = 0; i < 3; ++i)
        #pragma unroll
        for (int j = 0; j < 3; ++j)
            P[i][j] = b[12] * A6[i][j] + b[10] * A4[i][j] + b[8] * A2[i][j];
    mm3f(A6, P, T);
    #pragma unroll
    for (int i = 0; i < 3; ++i)
        #pragma unroll
        for (int j = 0; j < 3; ++j)
            V[i][j] = T[i][j] + b[6] * A6[i][j] + b[4] * A4[i][j] + b[2] * A2[i][j]
                      + (i == j ? b[0] : 0.0f);

    float M[3][6];
    #pragma unroll
    for (int i = 0; i < 3; ++i)
        #pragma unroll
        for (int j = 0; j < 3; ++j) {
            M[i][j]     = U[i][j] + V[i][j];
            M[i][j + 3] = V[i][j] - U[i][j];
        }
    #pragma unroll
    for (int col = 0; col < 3; ++col) {
        int piv = col;
        float best = fabsf(M[col][col]);
        for (int r = col + 1; r < 3; ++r) {
            float v = fabsf(M[r][col]);
            if (v > best) { best = v; piv = r; }
        }
        if (piv != col) {
            #pragma unroll
            for (int j = 0; j < 6; ++j) {
                float t = M[col][j]; M[col][j] = M[piv][j]; M[piv][j] = t;
            }
        }
        float inv = 1.0f / M[col][col];
        #pragma unroll
        for (int j = 0; j < 6; ++j) M[col][j] *= inv;
        #pragma unroll
        for (int r = 0; r < 3; ++r) {
            if (r == col) continue;
            float f = M[r][col];
            #pragma unroll
            for (int j = 0; j < 6; ++j) M[r][j] -= f * M[col][j];
        }
    }
    float R[3][3];
    #pragma unroll
    for (int i = 0; i < 3; ++i)
        #pragma unroll
        for (int j = 0; j < 3; ++j) R[i][j] = M[i][j + 3];

    for (int i = 0; i < 16; ++i) {
        if (i < k) {
            float Rn[3][3];
            mm3f(R, R, Rn);
            #pragma unroll
            for (int a = 0; a < 3; ++a)
                #pragma unroll
                for (int c = 0; c < 3; ++c) R[a][c] = Rn[a][c];
        }
    }

    #pragma unroll
    for (int j = 0; j < 3; ++j) {
        thOut[n * 6 + j]     = (float)R[0][j];
        thOut[n * 6 + 3 + j] = (float)R[1][j];
    }
}

// Fused affine_grid + bilinear grid_sample (zeros padding, align_corners=True).
// Block = 32x32 output tile; 256 threads, each a 2x2 quad.
// Phase 1 (unchanged from R8): stage the block-uniform input window (56 cols
//   x rn+1 rows x 3 ch) via global_load_lds dwordx4, linear LDS dest.
// Phase 2: INTERIOR blocks (bbox fully inside the image — block-uniform test)
//   skip all masks and clamps, and read corner pairs as lds[b+K]/lds[b+K+1]
//   with compile-time deltas so they fuse to ds_read2_b32 (halves LDS instr
//   count and conflict cycles; quad lane-stride-2 makes scalar reads 4-way
//   even-bank conflicted). EDGE blocks keep the R8 per-corner-clamped path
//   (any clamp-displaced slot provably carries weight 0).
__global__ __launch_bounds__(256) void sample_kernel(const float* __restrict__ x,
                                                     const float* __restrict__ th,
                                                     float* __restrict__ out) {
    __shared__ float lds[10240];  // 2560 chunks * 16B = 40960 B

    // 8x8 tiles/image * 128 images = 8192 blocks; bijective XCD swizzle
    const int nwg_per_xcd = 8192 / 8;
    int bid = blockIdx.x;
    int wgid = (bid & 7) * nwg_per_xcd + (bid >> 3);

    int tw  = wgid & 7;
    int thp = (wgid >> 3) & 7;
    int n   = wgid >> 6;

    int tid = threadIdx.x;
    int wp = tid & 15, hp = tid >> 4;
    int w0 = (tw << 5) + (wp << 1);
    int h0 = (thp << 5) + (hp << 1);

    const float* t = th + n * 6;
    float t0 = t[0], t1 = t[1], t2 = t[2], t3 = t[3], t4 = t[4], t5 = t[5];

    float Cx = 127.5f * (t2 - t0 - t1 + 1.0f);
    float Cy = 127.5f * (t5 - t3 - t4 + 1.0f);

    // block-uniform bounding box of sample coords (pad +-1 for fp slack, +1 corner)
    float fwA = (float)(tw << 5),  fwB = fwA + 31.0f;
    float fhA = (float)(thp << 5), fhB = fhA + 31.0f;
    float xlo = fminf(fwA * t0, fwB * t0) + fminf(fhA * t1, fhB * t1) + Cx;
    float xhi = fmaxf(fwA * t0, fwB * t0) + fmaxf(fhA * t1, fhB * t1) + Cx;
    float ylo = fminf(fwA * t3, fwB * t3) + fminf(fhA * t4, fhB * t4) + Cy;
    float yhi = fmaxf(fwA * t3, fwB * t3) + fmaxf(fhA * t4, fhB * t4) + Cy;
    int Xlo = (int)floorf(xlo) - 1, Xhi = (int)floorf(xhi) + 2;
    int Ylo = (int)floorf(ylo) - 1, Yhi = (int)floorf(yhi) + 2;
    int cn = Xhi - Xlo + 1;
    int rn = Yhi - Ylo + 1;

    size_t nbase = (size_t)n * Cdim * HW;

    // quad sample coords
    float ix00 = fmaf((float)w0, t0, fmaf((float)h0, t1, Cx));
    float iy00 = fmaf((float)w0, t3, fmaf((float)h0, t4, Cy));
    float ixq[2][2] = {{ix00, ix00 + t0}, {ix00 + t1, ix00 + t0 + t1}};
    float iyq[2][2] = {{iy00, iy00 + t3}, {iy00 + t4, iy00 + t3 + t4}};

    bool fast = (cn <= 52) && (rn <= 55) && (rn >= 1) && (cn >= 1);

    if (fast) {
        int bxw = (min(max(Xlo, 0), Wdim - 56)) & ~3;  // 16B-aligned window base col
        int byw = min(max(Ylo, 0), Hdim - rn);

        // ---- Phase 1: stage (rn+1) rows x 56 cols x 3 ch ----
        int totc  = 42 * (rn + 1);           // 16B chunks (42 = 3ch * 14 chunks/row)
        int iters = (totc + 255) >> 8;       // <= 10
        const float* gbase = x + nbase;
        for (int it = 0; it < iters; ++it) {
            int c = (it << 8) + tid;
            int row = c / 42;
            int rem = c - row * 42;
            row = min(row, rn);                       // overshoot -> re-stage last row
            int ch   = rem / 14;
            int colc = rem - ch * 14;
            int srow = min(byw + row, Hdim - 1);      // extra row clamped in-image
            const float* gp = gbase + (size_t)ch * HW + (srow << 8) + bxw + (colc << 2);
            __builtin_amdgcn_global_load_lds(
                (const __attribute__((address_space(1))) uint32*)gp,
                (__attribute__((address_space(3))) uint32*)((uint32*)lds + ((size_t)c << 2)),
                16, 0, 0);
        }
        __syncthreads();

        bool interior = (Xlo >= 0) && (Xhi <= Wdim - 1) && (Ylo >= 0) && (Yhi <= Hdim - 1);

        float res[2][2][3];
        if (interior) {
            // ---- Phase 2a: interior — no masks, no clamps, paired LDS reads ----
            #pragma unroll
            for (int p = 0; p < 2; ++p)
                #pragma unroll
                for (int q = 0; q < 2; ++q) {
                    float ix = ixq[p][q], iy = iyq[p][q];
                    float fx = floorf(ix), fy = floorf(iy);
                    int x0i = (int)fx, y0i = (int)fy;
                    float wx1 = ix - fx, wx0 = 1.0f - wx1;
                    float wy1 = iy - fy, wy0 = 1.0f - wy1;

                    int lx = x0i - bxw;              // in [0,54]
                    int ly = y0i - byw;              // in [0,rn-2]
                    int base = ly * 168 + lx;        // [row][ch][56] dword index
                    #pragma unroll
                    for (int c = 0; c < Cdim; ++c) {
                        const float* bp = lds + base + c * 56;
                        float v00 = bp[0],   v01 = bp[1];     // fuse -> ds_read2_b32
                        float v10 = bp[168], v11 = bp[169];   // fuse -> ds_read2_b32
                        float top = fmaf(v01, wx1, v00 * wx0);
                        float bot = fmaf(v11, wx1, v10 * wx0);
                        res[p][q][c] = fmaf(wy1, bot, wy0 * top);
                    }
                }
        } else {
            // ---- Phase 2b: edge — per-corner clamped slots (R8 path) ----
            #pragma unroll
            for (int p = 0; p < 2; ++p)
                #pragma unroll
                for (int q = 0; q < 2; ++q) {
                    float ix = ixq[p][q], iy = iyq[p][q];
                    float fx = floorf(ix), fy = floorf(iy);
                    int x0i = (int)fx, y0i = (int)fy;
                    float wx1 = ix - fx, wx0 = 1.0f - wx1;
                    float wy1 = iy - fy, wy0 = 1.0f - wy1;
                    float mx0 = ((unsigned)x0i       < (unsigned)Wdim) ? 1.0f : 0.0f;
                    float mx1 = ((unsigned)(x0i + 1) < (unsigned)Wdim) ? 1.0f : 0.0f;
                    float my0 = ((unsigned)y0i       < (unsigned)Hdim) ? 1.0f : 0.0f;
                    float my1 = ((unsigned)(y0i + 1) < (unsigned)Hdim) ? 1.0f : 0.0f;
                    float wxm0 = wx0 * mx0, wxm1 = wx1 * mx1;
                    float wym0 = wy0 * my0, wym1 = wy1 * my1;

                    int lx0 = min(max(x0i - bxw, 0), 55);
                    int lx1 = min(max(x0i + 1 - bxw, 0), 55);
                    int ly0 = min(max(y0i - byw, 0), rn);
                    int ly1 = min(max(y0i + 1 - byw, 0), rn);
                    int r0 = ly0 * 168, r1 = ly1 * 168;
                    #pragma unroll
                    for (int c = 0; c < Cdim; ++c) {
                        int b0 = r0 + c * 56;
                        int b1 = r1 + c * 56;
                        float v00 = lds[b0 + lx0], v01 = lds[b0 + lx1];
                        float v10 = lds[b1 + lx0], v11 = lds[b1 + lx1];
                        float top = fmaf(v01, wxm1, v00 * wxm0);
                        float bot = fmaf(v11, wxm1, v10 * wxm0);
                        res[p][q][c] = fmaf(wym1, bot, wym0 * top);
                    }
                }
        }

        size_t p0 = (size_t)h0 * Wdim + w0;
        #pragma unroll
        for (int c = 0; c < Cdim; ++c) {
            vf2 r0 = {res[0][0][c], res[0][1][c]};
            vf2 r1 = {res[1][0][c], res[1][1][c]};
            __builtin_nontemporal_store(r0, (vf2*)(out + nbase + (size_t)c * HW + p0));
            __builtin_nontemporal_store(r1, (vf2*)(out + nbase + (size_t)c * HW + p0 + Wdim));
        }
    } else {
        // exact fallback: per-pixel global gathers (block-uniform branch)
        const float* img0 = x + nbase;
        #pragma unroll
        for (int p = 0; p < 2; ++p)
            #pragma unroll
            for (int q = 0; q < 2; ++q) {
                float ix = ixq[p][q], iy = iyq[p][q];
                float fx = floorf(ix), fy = floorf(iy);
                int ix0 = (int)fx, iy0 = (int)fy;
                float wx1 = ix - fx, wx0 = 1.0f - wx1;
                float wy1 = iy - fy, wy0 = 1.0f - wy1;
                float mx0 = ((unsigned)ix0       < (unsigned)Wdim) ? 1.0f : 0.0f;
                float mx1 = ((unsigned)(ix0 + 1) < (unsigned)Wdim) ? 1.0f : 0.0f;
                float my0 = ((unsigned)iy0       < (unsigned)Hdim) ? 1.0f : 0.0f;
                float my1 = ((unsigned)(iy0 + 1) < (unsigned)Hdim) ? 1.0f : 0.0f;
                int xc0 = min(max(ix0, 0), Wdim - 1);
                int xc1 = min(max(ix0 + 1, 0), Wdim - 1);
                int yc0 = min(max(iy0, 0), Hdim - 1);
                int yc1 = min(max(iy0 + 1, 0), Hdim - 1);
                float w00 = wy0 * wx0 * my0 * mx0;
                float w01 = wy0 * wx1 * my0 * mx1;
                float w10 = wy1 * wx0 * my1 * mx0;
                float w11 = wy1 * wx1 * my1 * mx1;
                int o00 = yc0 * Wdim + xc0, o01 = yc0 * Wdim + xc1;
                int o10 = yc1 * Wdim + xc0, o11 = yc1 * Wdim + xc1;
                #pragma unroll
                for (int c = 0; c < Cdim; ++c) {
                    const float* img = img0 + (size_t)c * HW;
                    float r = fmaf(img[o00], w00, fmaf(img[o01], w01,
                              fmaf(img[o10], w10, img[o11] * w11)));
                    out[nbase + (size_t)c * HW + (size_t)(h0 + p) * Wdim + (w0 + q)] = r;
                }
            }
    }
}

extern "C" void kernel_launch(void* const* d_in, const int* in_sizes, int n_in,
                              void* d_out, int out_size, void* d_ws, size_t ws_size,
                              hipStream_t stream) {
    const float* x     = (const float*)d_in[0];
    const float* theta = (const float*)d_in[1];
    float* out = (float*)d_out;
    float* th  = (float*)d_ws;  // 128*6 floats of scratch

    expm_kernel<<<1, 128, 0, stream>>>(theta, th);

    int nblocks = 8192;
    sample_kernel<<<nblocks, 256, 0, stream>>>(x, th, out);
}

// Round 10
// 40.917 us; speedup vs baseline: 1.0588x; 1.0479x over previous
//
#include <hip/hip_runtime.h>

#define Ndim 128
#define Cdim 3
#define Hdim 256
#define Wdim 256
#define HW (Hdim * Wdim)
#define MAXNORM_F 5.371920351148152f

typedef float vf2 __attribute__((ext_vector_type(2)));
typedef unsigned int uint32;

__device__ __forceinline__ void mm3f(const float a[3][3], const float b[3][3], float c[3][3]) {
    #pragma unroll
    for (int i = 0; i < 3; ++i)
        #pragma unroll
        for (int j = 0; j < 3; ++j) {
            float s = 0.0f;
            #pragma unroll
            for (int k = 0; k < 3; ++k) s = fmaf(a[i][k], b[k][j], s);
            c[i][j] = s;
        }
}

// One thread per batch element: expm of padded 3x3 affine matrix (fp32 Pade-13).
__global__ void expm_kernel(const float* __restrict__ theta, float* __restrict__ thOut) {
    int n = blockIdx.x * blockDim.x + threadIdx.x;
    if (n >= Ndim) return;

    const float b[14] = {6.476475253248e+16f, 3.238237626624e+16f, 7771770303897600.0f,
                         1187353796428800.0f, 129060195264000.0f, 10559470521600.0f,
                         670442572800.0f, 33522128640.0f, 1323241920.0f, 40840800.0f,
                         960960.0f, 16380.0f, 182.0f, 1.0f};

    float A[3][3];
    #pragma unroll
    for (int j = 0; j < 3; ++j) {
        A[0][j] = theta[n * 6 + j];
        A[1][j] = theta[n * 6 + 3 + j];
        A[2][j] = 0.0f;
    }

    float fro2 = 0.0f;
    #pragma unroll
    for (int i = 0; i < 3; ++i)
        #pragma unroll
        for (int j = 0; j < 3; ++j) fro2 = fmaf(A[i][j], A[i][j], fro2);
    float fro = sqrtf(fro2);

    float nsq = fmaxf(0.0f, ceilf(log2f(fro / MAXNORM_F)));
    int k = (int)nsq;
    float sc = exp2f(-nsq);
    #pragma unroll
    for (int i = 0; i < 3; ++i)
        #pragma unroll
        for (int j = 0; j < 3; ++j) A[i][j] *= sc;

    float A2[3][3], A4[3][3], A6[3][3], P[3][3], Wm[3][3], T[3][3], U[3][3], V[3][3];
    mm3f(A, A, A2);
    mm3f(A2, A2, A4);
    mm3f(A4, A2, A6);

    #pragma unroll
    for (int i = 0; i < 3; ++i)
        #pragma unroll
        for (int j = 0; j < 3; ++j)
            P[i][j] = b[13] * A6[i][j] + b[11] * A4[i][j] + b[9] * A2[i][j];
    mm3f(A6, P, T);
    #pragma unroll
    for (int i = 0; i < 3; ++i)
        #pragma unroll
        for (int j = 0; j < 3; ++j)
            Wm[i][j] = T[i][j] + b[7] * A6[i][j] + b[5] * A4[i][j] + b[3] * A2[i][j]
                       + (i == j ? b[1] : 0.0f);
    mm3f(A, Wm, U);

    #pragma unroll
    for (int i = 0; i < 3; ++i)
        #pragma unroll
        for (int j = 0; j < 3; ++j)
            P[i][j] = b[12] * A6[i][j] + b[10] * A4[i][j] + b[8] * A2[i][j];
    mm3f(A6, P, T);
    #pragma unroll
    for (int i = 0; i < 3; ++i)
        #pragma unroll
        for (int j = 0; j < 3; ++j)
            V[i][j] = T[i][j] + b[6] * A6[i][j] + b[4] * A4[i][j] + b[2] * A2[i][j]
                      + (i == j ? b[0] : 0.0f);

    float M[3][6];
    #pragma unroll
    for (int i = 0; i < 3; ++i)
        #pragma unroll
        for (int j = 0; j < 3; ++j) {
            M[i][j]     = U[i][j] + V[i][j];
            M[i][j + 3] = V[i][j] - U[i][j];
        }
    #pragma unroll
    for (int col = 0; col < 3; ++col) {
        int piv = col;
        float best = fabsf(M[col][col]);
        for (int r = col + 1; r < 3; ++r) {
            float v = fabsf(M[r][col]);
            if (v > best) { best = v; piv = r; }
        }
        if (piv != col) {
            #pragma unroll
            for (int j = 0; j < 6; ++j) {
                float t = M[col][j]; M[col][j] = M[piv][j]; M[piv][j] = t;
            }
        }
        float inv = 1.0f / M[col][col];
        #pragma unroll
        for (int j = 0; j < 6; ++j) M[col][j] *= inv;
        #pragma unroll
        for (int r = 0; r < 3; ++r) {
            if (r == col) continue;
            float f = M[r][col];
            #pragma unroll
            for (int j = 0; j < 6; ++j) M[r][j] -= f * M[col][j];
        }
    }
    float R[3][3];
    #pragma unroll
    for (int i = 0; i < 3; ++i)
        #pragma unroll
        for (int j = 0; j < 3; ++j) R[i][j] = M[i][j + 3];

    for (int i = 0; i < 16; ++i) {
        if (i < k) {
            float Rn[3][3];
            mm3f(R, R, Rn);
            #pragma unroll
            for (int a = 0; a < 3; ++a)
                #pragma unroll
                for (int c = 0; c < 3; ++c) R[a][c] = Rn[a][c];
        }
    }

    #pragma unroll
    for (int j = 0; j < 3; ++j) {
        thOut[n * 6 + j]     = (float)R[0][j];
        thOut[n * 6 + 3 + j] = (float)R[1][j];
    }
}

// Fused affine_grid + bilinear grid_sample (zeros padding, align_corners=True).
// Block = 32x32 output tile; 256 threads, each a 1-wide x 4-tall strip
// (w = tile + (tid&31): lane lx stride is 1 -> lanes 0..31 hit 32 distinct
// banks; lanes 32..63 are +4 rows = bank shift 8*4 == 0 mod 32 -> 2 lanes/bank
// = conflict-free. The R8/R9 2x2-quad layout had lx stride 2: all 64 lanes on
// the 16 even banks = systematic 4-way conflict (4.5M cycles/dispatch).
// Phase 1 (unchanged): stage block-uniform window (56 cols x rn+1 rows x 3ch)
// via global_load_lds dwordx4, linear LDS dest, layout [row][ch][56].
// Phase 2: interior blocks mask/clamp-free with paired reads (ds_read2_b32);
// edge blocks per-corner-clamped (displaced slot => weight 0). Non-fast
// blocks: exact global-gather fallback.
__global__ __launch_bounds__(256) void sample_kernel(const float* __restrict__ x,
                                                     const float* __restrict__ th,
                                                     float* __restrict__ out) {
    __shared__ float lds[10240];  // 2560 chunks * 16B = 40960 B

    // 8x8 tiles/image * 128 images = 8192 blocks; bijective XCD swizzle
    const int nwg_per_xcd = 8192 / 8;
    int bid = blockIdx.x;
    int wgid = (bid & 7) * nwg_per_xcd + (bid >> 3);

    int tw  = wgid & 7;
    int thp = (wgid >> 3) & 7;
    int n   = wgid >> 6;

    int tid = threadIdx.x;
    int w  = (tw << 5) + (tid & 31);        // lane-consecutive column
    int h0 = (thp << 5) + ((tid >> 5) << 2); // 4 rows h0..h0+3

    const float* t = th + n * 6;
    float t0 = t[0], t1 = t[1], t2 = t[2], t3 = t[3], t4 = t[4], t5 = t[5];

    float Cx = 127.5f * (t2 - t0 - t1 + 1.0f);
    float Cy = 127.5f * (t5 - t3 - t4 + 1.0f);

    // block-uniform bounding box of sample coords (pad +-1 fp slack, +1 corner)
    float fwA = (float)(tw << 5),  fwB = fwA + 31.0f;
    float fhA = (float)(thp << 5), fhB = fhA + 31.0f;
    float xlo = fminf(fwA * t0, fwB * t0) + fminf(fhA * t1, fhB * t1) + Cx;
    float xhi = fmaxf(fwA * t0, fwB * t0) + fmaxf(fhA * t1, fhB * t1) + Cx;
    float ylo = fminf(fwA * t3, fwB * t3) + fminf(fhA * t4, fhB * t4) + Cy;
    float yhi = fmaxf(fwA * t3, fwB * t3) + fmaxf(fhA * t4, fhB * t4) + Cy;
    int Xlo = (int)floorf(xlo) - 1, Xhi = (int)floorf(xhi) + 2;
    int Ylo = (int)floorf(ylo) - 1, Yhi = (int)floorf(yhi) + 2;
    int cn = Xhi - Xlo + 1;
    int rn = Yhi - Ylo + 1;

    size_t nbase = (size_t)n * Cdim * HW;

    // strip sample coords: px p at (w, h0+p)
    float ixs[4], iys[4];
    float ixb = fmaf((float)w, t0, fmaf((float)h0, t1, Cx));
    float iyb = fmaf((float)w, t3, fmaf((float)h0, t4, Cy));
    #pragma unroll
    for (int p = 0; p < 4; ++p) {
        ixs[p] = fmaf((float)p, t1, ixb);
        iys[p] = fmaf((float)p, t4, iyb);
    }

    bool fast = (cn <= 52) && (rn <= 55) && (rn >= 1) && (cn >= 1);

    if (fast) {
        int bxw = (min(max(Xlo, 0), Wdim - 56)) & ~3;  // 16B-aligned window base col
        int byw = min(max(Ylo, 0), Hdim - rn);

        // ---- Phase 1: stage (rn+1) rows x 56 cols x 3 ch ----
        int totc  = 42 * (rn + 1);           // 16B chunks (42 = 3ch * 14 chunks/row)
        int iters = (totc + 255) >> 8;       // <= 10
        const float* gbase = x + nbase;
        for (int it = 0; it < iters; ++it) {
            int c = (it << 8) + tid;
            int row = c / 42;
            int rem = c - row * 42;
            row = min(row, rn);                       // overshoot -> re-stage last row
            int ch   = rem / 14;
            int colc = rem - ch * 14;
            int srow = min(byw + row, Hdim - 1);      // extra row clamped in-image
            const float* gp = gbase + (size_t)ch * HW + (srow << 8) + bxw + (colc << 2);
            __builtin_amdgcn_global_load_lds(
                (const __attribute__((address_space(1))) uint32*)gp,
                (__attribute__((address_space(3))) uint32*)((uint32*)lds + ((size_t)c << 2)),
                16, 0, 0);
        }
        __syncthreads();

        bool interior = (Xlo >= 0) && (Xhi <= Wdim - 1) && (Ylo >= 0) && (Yhi <= Hdim - 1);

        float res[4][3];
        if (interior) {
            // ---- Phase 2a: interior — no masks/clamps, paired LDS reads ----
            #pragma unroll
            for (int p = 0; p < 4; ++p) {
                float ix = ixs[p], iy = iys[p];
                float fx = floorf(ix), fy = floorf(iy);
                int x0i = (int)fx, y0i = (int)fy;
                float wx1 = ix - fx, wx0 = 1.0f - wx1;
                float wy1 = iy - fy, wy0 = 1.0f - wy1;

                int lx = x0i - bxw;              // in [0,54]
                int ly = y0i - byw;              // in [0,rn-2]
                int base = ly * 168 + lx;        // [row][ch][56] dword index
                #pragma unroll
                for (int c = 0; c < Cdim; ++c) {
                    const float* bp = lds + base + c * 56;
                    float v00 = bp[0],   v01 = bp[1];     // fuse -> ds_read2_b32
                    float v10 = bp[168], v11 = bp[169];   // fuse -> ds_read2_b32
                    float top = fmaf(v01, wx1, v00 * wx0);
                    float bot = fmaf(v11, wx1, v10 * wx0);
                    res[p][c] = fmaf(wy1, bot, wy0 * top);
                }
            }
        } else {
            // ---- Phase 2b: edge — per-corner clamped slots ----
            #pragma unroll
            for (int p = 0; p < 4; ++p) {
                float ix = ixs[p], iy = iys[p];
                float fx = floorf(ix), fy = floorf(iy);
                int x0i = (int)fx, y0i = (int)fy;
                float wx1 = ix - fx, wx0 = 1.0f - wx1;
                float wy1 = iy - fy, wy0 = 1.0f - wy1;
                float mx0 = ((unsigned)x0i       < (unsigned)Wdim) ? 1.0f : 0.0f;
                float mx1 = ((unsigned)(x0i + 1) < (unsigned)Wdim) ? 1.0f : 0.0f;
                float my0 = ((unsigned)y0i       < (unsigned)Hdim) ? 1.0f : 0.0f;
                float my1 = ((unsigned)(y0i + 1) < (unsigned)Hdim) ? 1.0f : 0.0f;
                float wxm0 = wx0 * mx0, wxm1 = wx1 * mx1;
                float wym0 = wy0 * my0, wym1 = wy1 * my1;

                int lx0 = min(max(x0i - bxw, 0), 55);
                int lx1 = min(max(x0i + 1 - bxw, 0), 55);
                int ly0 = min(max(y0i - byw, 0), rn);
                int ly1 = min(max(y0i + 1 - byw, 0), rn);
                int r0 = ly0 * 168, r1 = ly1 * 168;
                #pragma unroll
                for (int c = 0; c < Cdim; ++c) {
                    int b0 = r0 + c * 56;
                    int b1 = r1 + c * 56;
                    float v00 = lds[b0 + lx0], v01 = lds[b0 + lx1];
                    float v10 = lds[b1 + lx0], v11 = lds[b1 + lx1];
                    float top = fmaf(v01, wxm1, v00 * wxm0);
                    float bot = fmaf(v11, wxm1, v10 * wxm0);
                    res[p][c] = fmaf(wym1, bot, wym0 * top);
                }
            }
        }

        size_t p0 = (size_t)h0 * Wdim + w;
        #pragma unroll
        for (int c = 0; c < Cdim; ++c)
            #pragma unroll
            for (int p = 0; p < 4; ++p)
                __builtin_nontemporal_store(res[p][c],
                    out + nbase + (size_t)c * HW + p0 + (size_t)p * Wdim);
    } else {
        // exact fallback: per-pixel global gathers (block-uniform branch)
        const float* img0 = x + nbase;
        #pragma unroll
        for (int p = 0; p < 4; ++p) {
            float ix = ixs[p], iy = iys[p];
            float fx = floorf(ix), fy = floorf(iy);
            int ix0 = (int)fx, iy0 = (int)fy;
            float wx1 = ix - fx, wx0 = 1.0f - wx1;
            float wy1 = iy - fy, wy0 = 1.0f - wy1;
            float mx0 = ((unsigned)ix0       < (unsigned)Wdim) ? 1.0f : 0.0f;
            float mx1 = ((unsigned)(ix0 + 1) < (unsigned)Wdim) ? 1.0f : 0.0f;
            float my0 = ((unsigned)iy0       < (unsigned)Hdim) ? 1.0f : 0.0f;
            float my1 = ((unsigned)(iy0 + 1) < (unsigned)Hdim) ? 1.0f : 0.0f;
            int xc0 = min(max(ix0, 0), Wdim - 1);
            int xc1 = min(max(ix0 + 1, 0), Wdim - 1);
            int yc0 = min(max(iy0, 0), Hdim - 1);
            int yc1 = min(max(iy0 + 1, 0), Hdim - 1);
            float w00 = wy0 * wx0 * my0 * mx0;
            float w01 = wy0 * wx1 * my0 * mx1;
            float w10 = wy1 * wx0 * my1 * mx0;
            float w11 = wy1 * wx1 * my1 * mx1;
            int o00 = yc0 * Wdim + xc0, o01 = yc0 * Wdim + xc1;
            int o10 = yc1 * Wdim + xc0, o11 = yc1 * Wdim + xc1;
            #pragma unroll
            for (int c = 0; c < Cdim; ++c) {
                const float* img = img0 + (size_t)c * HW;
                float r = fmaf(img[o00], w00, fmaf(img[o01], w01,
                          fmaf(img[o10], w10, img[o11] * w11)));
                out[nbase + (size_t)c * HW + (size_t)(h0 + p) * Wdim + w] = r;
            }
        }
    }
}

extern "C" void kernel_launch(void* const* d_in, const int* in_sizes, int n_in,
                              void* d_out, int out_size, void* d_ws, size_t ws_size,
                              hipStream_t stream) {
    const float* x     = (const float*)d_in[0];
    const float* theta = (const float*)d_in[1];
    float* out = (float*)d_out;
    float* th  = (float*)d_ws;  // 128*6 floats of scratch

    expm_kernel<<<1, 128, 0, stream>>>(theta, th);

    int nblocks = 8192;
    sample_kernel<<<nblocks, 256, 0, stream>>>(x, th, out);
}